// Round 18
// baseline (106.814 us; speedup 1.0000x reference)
//
#include <hip/hip_runtime.h>

typedef __bf16 bf16x8 __attribute__((ext_vector_type(8)));
typedef float f32x4 __attribute__((ext_vector_type(4)));

#define BN_EPS 1e-5f

__device__ __forceinline__ unsigned short f2bf(float f) {
    union { float f; unsigned u; } x; x.f = f;
    unsigned r = x.u + 0x7fffu + ((x.u >> 16) & 1u);
    return (unsigned short)(r >> 16);
}

__device__ __forceinline__ unsigned pk_bf16(float lo, float hi) {
    unsigned r;
    asm("v_cvt_pk_bf16_f32 %0, %1, %2" : "=v"(r) : "v"(lo), "v"(hi));
    return r;
}

__device__ __forceinline__ float fcomp(float4 v, int j) {
    return (j == 0) ? v.x : (j == 1) ? v.y : (j == 2) ? v.z : v.w;
}

// ---------------- prepass: fold BN scale into weights, FRAGMENT-CONTIGUOUS layout ----
__global__ void prep_kernel(const float* __restrict__ pw0, const float* __restrict__ pw1,
                            const float* __restrict__ w2,
                            const float* __restrict__ s0, const float* __restrict__ b0,
                            const float* __restrict__ m0, const float* __restrict__ v0,
                            const float* __restrict__ s1, const float* __restrict__ b1,
                            const float* __restrict__ m1, const float* __restrict__ v1,
                            const float* __restrict__ s2, const float* __restrict__ b2,
                            const float* __restrict__ m2, const float* __restrict__ v2,
                            unsigned short* __restrict__ wfF0, unsigned short* __restrict__ wfF1,
                            unsigned short* __restrict__ wfF2, float* __restrict__ beta) {
    int o = blockIdx.x;
    int t = threadIdx.x;
    float inv0 = s0[o] * rsqrtf(v0[o] + BN_EPS);
    float inv1 = s1[o] * rsqrtf(v1[o] + BN_EPS);
    float inv2 = s2[o] * rsqrtf(v2[o] + BN_EPS);
    if (t == 0) {
        beta[0 * 256 + o] = b0[o] - m0[o] * inv0;
        beta[1 * 256 + o] = b1[o] - m1[o] * inv1;
        beta[2 * 256 + o] = b2[o] - m2[o] * inv2;
    }
    if (t < 128) {
        wfF0[((t >> 3) * 256 + o) * 8 + (t & 7)] = f2bf(pw0[o * 128 + t] * inv0);
        wfF1[((t >> 3) * 256 + o) * 8 + (t & 7)] = f2bf(pw1[o * 128 + t] * inv1);
    }
    wfF2[((t >> 3) * 256 + o) * 8 + (t & 7)] = f2bf(w2[o * 256 + t] * inv2);
}

// ---------------- GEMM helper: chunked A-preload (4 kk in flight) ---------------------
// B-tile: [64 px][256 K] bf16, px-major 512 B/px, 16-B col c stored at c ^ ((px&15)<<4).
template<int NK>
__device__ __forceinline__ void gemm_expert(const char* lds, const unsigned short* __restrict__ W,
                                            int qb, int wave, int l15, int l4,
                                            const int* pxv, const int* swv, f32x4 acc[2][4]) {
    const int row0 = wave * 32 + l15;
#pragma unroll
    for (int ck = 0; ck < NK; ck += 4) {
        // A-chunk: 8 fragments (32 VGPRs), one independent L2 round-trip
        bf16x8 af[4][2];
#pragma unroll
        for (int kk = 0; kk < 4; ++kk)
#pragma unroll
            for (int ot = 0; ot < 2; ++ot)
                af[kk][ot] = *(const bf16x8*)(W + (((ck + kk) * 4 + l4) * 256 + row0 + ot * 16) * 8);
#pragma unroll
        for (int kk = 0; kk < 4; ++kk) {
            bf16x8 bb[4];
#pragma unroll
            for (int tp = 0; tp < 4; ++tp)
                bb[tp] = *(const bf16x8*)(lds + pxv[tp] * 512 + ((qb + (ck + kk) * 64 + l4 * 16) ^ swv[tp]));
#pragma unroll
            for (int ot = 0; ot < 2; ++ot)
#pragma unroll
                for (int tp = 0; tp < 4; ++tp)
                    acc[ot][tp] = __builtin_amdgcn_mfma_f32_16x16x32_bf16(af[kk][ot], bb[tp], acc[ot][tp], 0, 0, 0);
        }
    }
}

__device__ __forceinline__ void epilogue(const f32x4 acc[2][4], float ce, const float* __restrict__ bp,
                                         int wave, int l4, f32x4 res[2][4]) {
#pragma unroll
    for (int ot = 0; ot < 2; ++ot)
#pragma unroll
        for (int j = 0; j < 4; ++j) {
            const int o = wave * 32 + ot * 16 + l4 * 4 + j;
            const float bet = bp[o];
#pragma unroll
            for (int tp = 0; tp < 4; ++tp) {
                float v = acc[ot][tp][j] + bet;
                float sig = __builtin_amdgcn_rcpf(1.f + __expf(-v));
                res[ot][tp][j] += ce * (v * sig);
            }
        }
}

// ---------------- main fused kernel: 1 WG per (b,h) row, 8 waves, SINGLE staging pass --
// LDS: [0,32K) dw B-tile; [32K,64K) raw B-tile; store transpose reuses [0,34.8K).
__global__ __launch_bounds__(512, 3)
void fused_kernel(const float* __restrict__ x,
                  const float* __restrict__ wts, const int* __restrict__ idx,
                  const float* __restrict__ dw0, const float* __restrict__ dw1,
                  const unsigned short* __restrict__ wfF0,
                  const unsigned short* __restrict__ wfF1,
                  const unsigned short* __restrict__ wfF2,
                  const float* __restrict__ beta,
                  float* __restrict__ out) {
    __shared__ __align__(16) char lds[69632];

    const int tid  = threadIdx.x;
    const int wave = tid >> 6;
    const int lane = tid & 63;

    // Stripe swizzle (r15): XCD x handles h-stripe [8x,8x+8) of every batch.
    const int bid = blockIdx.x;
    const int xcd = bid & 7;
    const int j   = bid >> 3;                        // 0..255
    const int b   = j >> 3;                          // 0..31
    const int h   = xcd * 8 + (j & 7);               // 0..63

    float c0 = 0.f, c1 = 0.f, c2 = 0.f;
#pragma unroll
    for (int t = 0; t < 2; ++t) {
        int e = idx[b * 2 + t];
        float w = wts[b * 2 + t];
        if (e == 0) c0 += w;
        else if (e == 1) c1 += w;
        else if (e == 2) c2 += w;
    }
    const bool do0 = (c0 != 0.f), do1 = (c1 != 0.f), do2 = (c2 != 0.f);

    const long rowBase = (long)b * 1048576L;

    const int g   = lane >> 2;
    const int kq  = lane & 3;
    const int px0 = g * 4;
    const int l15 = lane & 15;
    const int l4  = lane >> 4;
    const float* xb = x + rowBase + h * 64 + px0;
    const bool hm = (h > 0), hp = (h < 63);

    int pxv[4], swv[4];
#pragma unroll
    for (int tp = 0; tp < 4; ++tp) {
        pxv[tp] = tp * 16 + l15;
        swv[tp] = (pxv[tp] & 15) << 4;
    }

    // ============ single merged staging: dw tile + raw tile from one burst ============
    const bool dwact = (wave < 4) ? do0 : do1;
    if (dwact || do2) {
        float4 RM[8], RC[8], RP[8];
        const float4 z4 = make_float4(0.f, 0.f, 0.f, 0.f);
#pragma unroll
        for (int c = 0; c < 8; ++c) {
            const int k = wave * 32 + ((c >> 2) << 4) + kq * 4 + (c & 3);
            const float* xc = xb + (long)k * 4096;
            RC[c] = *(const float4*)(xc);
            if (dwact) {
                RM[c] = hm ? *(const float4*)(xc - 64) : z4;
                RP[c] = hp ? *(const float4*)(xc + 64) : z4;
            }
        }
#pragma unroll
        for (int i = 0; i < 2; ++i) {
            const int k0 = wave * 32 + i * 16 + kq * 4;
            unsigned dw_p[2][4], rw_p[2][4];
#pragma unroll
            for (int pr = 0; pr < 2; ++pr) {
                float y[2][4];
#pragma unroll
                for (int k2 = 0; k2 < 2; ++k2) {
                    const int c = i * 4 + pr * 2 + k2;
                    const int k = k0 + pr * 2 + k2;
                    if (dwact) {
                        const float* dwp = (k < 128) ? (dw0 + k * 9) : (dw1 + (k - 128) * 9);
                        float4 rm = RM[c], rc = RC[c], rp = RP[c];
                        float lm = __shfl_up(rm.w, 4), lc = __shfl_up(rc.w, 4), lp = __shfl_up(rp.w, 4);
                        float Rm = __shfl_down(rm.x, 4), Rc = __shfl_down(rc.x, 4), Rp = __shfl_down(rp.x, 4);
                        if (g == 0)  { lm = 0.f; lc = 0.f; lp = 0.f; }
                        if (g == 15) { Rm = 0.f; Rc = 0.f; Rp = 0.f; }
                        const float w0 = dwp[0], w1 = dwp[1], w2 = dwp[2];
                        const float w3 = dwp[3], w4 = dwp[4], w5 = dwp[5];
                        const float w6 = dwp[6], w7 = dwp[7], w8 = dwp[8];
                        y[k2][0] = w0*lm   + w1*rm.x + w2*rm.y + w3*lc   + w4*rc.x + w5*rc.y + w6*lp   + w7*rp.x + w8*rp.y;
                        y[k2][1] = w0*rm.x + w1*rm.y + w2*rm.z + w3*rc.x + w4*rc.y + w5*rc.z + w6*rp.x + w7*rp.y + w8*rp.z;
                        y[k2][2] = w0*rm.y + w1*rm.z + w2*rm.w + w3*rc.y + w4*rc.z + w5*rc.w + w6*rp.y + w7*rp.z + w8*rp.w;
                        y[k2][3] = w0*rm.z + w1*rm.w + w2*Rm   + w3*rc.z + w4*rc.w + w5*Rc   + w6*rp.z + w7*rp.w + w8*Rp;
                    }
                }
                if (dwact) {
#pragma unroll
                    for (int j2 = 0; j2 < 4; ++j2)
                        dw_p[pr][j2] = pk_bf16(y[0][j2], y[1][j2]);
                }
                if (do2) {
                    const int c0i = i * 4 + pr * 2;
#pragma unroll
                    for (int j2 = 0; j2 < 4; ++j2)
                        rw_p[pr][j2] = pk_bf16(fcomp(RC[c0i], j2), fcomp(RC[c0i + 1], j2));
                }
            }
            const int colb = (k0 >> 3) * 16;
            const int sub  = (k0 & 4) * 2;
#pragma unroll
            for (int j2 = 0; j2 < 4; ++j2) {
                const int px  = px0 + j2;
                const int off = px * 512 + ((colb ^ ((px & 15) << 4))) + sub;
                if (dwact)
                    *(uint2*)(lds + off) = make_uint2(dw_p[0][j2], dw_p[1][j2]);
                if (do2)
                    *(uint2*)(lds + 32768 + off) = make_uint2(rw_p[0][j2], rw_p[1][j2]);
            }
        }
    }
    __syncthreads();

    // ============ GEMM phases, back-to-back (read-only LDS, no barriers) ============
    f32x4 res[2][4];
#pragma unroll
    for (int ot = 0; ot < 2; ++ot)
#pragma unroll
        for (int tp = 0; tp < 4; ++tp)
            res[ot][tp] = (f32x4){0.f, 0.f, 0.f, 0.f};

    if (do0) {
        f32x4 acc[2][4];
#pragma unroll
        for (int ot = 0; ot < 2; ++ot)
#pragma unroll
            for (int tp = 0; tp < 4; ++tp) acc[ot][tp] = (f32x4){0.f, 0.f, 0.f, 0.f};
        gemm_expert<4>(lds, wfF0, 0, wave, l15, l4, pxv, swv, acc);
        epilogue(acc, c0, beta, wave, l4, res);
    }
    if (do1) {
        f32x4 acc[2][4];
#pragma unroll
        for (int ot = 0; ot < 2; ++ot)
#pragma unroll
            for (int tp = 0; tp < 4; ++tp) acc[ot][tp] = (f32x4){0.f, 0.f, 0.f, 0.f};
        gemm_expert<4>(lds, wfF1, 256, wave, l15, l4, pxv, swv, acc);
        epilogue(acc, c1, beta + 256, wave, l4, res);
    }
    if (do2) {
        f32x4 acc[2][4];
#pragma unroll
        for (int ot = 0; ot < 2; ++ot)
#pragma unroll
            for (int tp = 0; tp < 4; ++tp) acc[ot][tp] = (f32x4){0.f, 0.f, 0.f, 0.f};
        gemm_expert<8>(lds + 32768, wfF2, 0, wave, l15, l4, pxv, swv, acc);
        epilogue(acc, c2, beta + 512, wave, l4, res);
    }

    // ================= store: transpose through LDS, full-line writes ================
    float* lf = (float*)lds;
    const long outB = rowBase + h * 64;
    __syncthreads();                                 // all GEMM reads done before overwrite
#pragma unroll
    for (int r = 0; r < 2; ++r) {
        if ((wave >> 2) == r) {
#pragma unroll
            for (int ot = 0; ot < 2; ++ot)
#pragma unroll
                for (int j2 = 0; j2 < 4; ++j2) {
                    const int o = wave * 32 + ot * 16 + l4 * 4 + j2;
#pragma unroll
                    for (int tp = 0; tp < 4; ++tp)
                        lf[(o & 127) * 68 + tp * 16 + l15] = res[ot][tp][j2];
                }
        }
        __syncthreads();
        {
            const int rowq = tid >> 3;
            const int col  = (tid & 7) * 8;
#pragma unroll
            for (int rr = 0; rr < 2; ++rr) {
                const int lr = rowq + rr * 64;
                float4 v0 = *(float4*)&lf[lr * 68 + col];
                float4 v1 = *(float4*)&lf[lr * 68 + col + 4];
                float* op = out + outB + (long)(r * 128 + lr) * 4096 + col;
                *(float4*)op = v0;
                *(float4*)(op + 4) = v1;
            }
        }
        __syncthreads();
    }
}

extern "C" void kernel_launch(void* const* d_in, const int* in_sizes, int n_in,
                              void* d_out, int out_size, void* d_ws, size_t ws_size,
                              hipStream_t stream) {
    const float* x    = (const float*)d_in[0];
    const float* wts  = (const float*)d_in[1];
    const int*   idx  = (const int*)d_in[2];
    const float* dw0  = (const float*)d_in[3];
    const float* pw0  = (const float*)d_in[4];
    const float* s0   = (const float*)d_in[5];
    const float* b0   = (const float*)d_in[6];
    const float* m0   = (const float*)d_in[7];
    const float* v0   = (const float*)d_in[8];
    const float* dw1  = (const float*)d_in[9];
    const float* pw1  = (const float*)d_in[10];
    const float* s1   = (const float*)d_in[11];
    const float* b1   = (const float*)d_in[12];
    const float* m1   = (const float*)d_in[13];
    const float* v1   = (const float*)d_in[14];
    const float* w2   = (const float*)d_in[15];
    const float* s2   = (const float*)d_in[16];
    const float* b2   = (const float*)d_in[17];
    const float* m2   = (const float*)d_in[18];
    const float* v2   = (const float*)d_in[19];

    char* ws = (char*)d_ws;
    unsigned short* wfF0 = (unsigned short*)ws;                 // 64 KB
    unsigned short* wfF1 = (unsigned short*)(ws + 65536);       // 64 KB
    unsigned short* wfF2 = (unsigned short*)(ws + 131072);      // 128 KB
    float*          beta = (float*)(ws + 262144);               // 3 KB

    prep_kernel<<<256, 256, 0, stream>>>(pw0, pw1, w2,
                                         s0, b0, m0, v0,
                                         s1, b1, m1, v1,
                                         s2, b2, m2, v2,
                                         wfF0, wfF1, wfF2, beta);

    fused_kernel<<<2048, 512, 0, stream>>>(x, wts, idx, dw0, dw1,
                                           wfF0, wfF1, wfF2, beta, (float*)d_out);
}

// Round 19
// 83.226 us; speedup vs baseline: 1.2834x; 1.2834x over previous
//
#include <hip/hip_runtime.h>

typedef __bf16 bf16x8 __attribute__((ext_vector_type(8)));
typedef float f32x4 __attribute__((ext_vector_type(4)));

#define BN_EPS 1e-5f

__device__ __forceinline__ unsigned short f2bf(float f) {
    union { float f; unsigned u; } x; x.f = f;
    unsigned r = x.u + 0x7fffu + ((x.u >> 16) & 1u);
    return (unsigned short)(r >> 16);
}

__device__ __forceinline__ unsigned pk_bf16(float lo, float hi) {
    unsigned r;
    asm("v_cvt_pk_bf16_f32 %0, %1, %2" : "=v"(r) : "v"(lo), "v"(hi));
    return r;
}

__device__ __forceinline__ float fcomp(float4 v, int j) {
    return (j == 0) ? v.x : (j == 1) ? v.y : (j == 2) ? v.z : v.w;
}

// ---------------- prepass: fold BN scale into weights, FRAGMENT-CONTIGUOUS layout ----
__global__ void prep_kernel(const float* __restrict__ pw0, const float* __restrict__ pw1,
                            const float* __restrict__ w2,
                            const float* __restrict__ s0, const float* __restrict__ b0,
                            const float* __restrict__ m0, const float* __restrict__ v0,
                            const float* __restrict__ s1, const float* __restrict__ b1,
                            const float* __restrict__ m1, const float* __restrict__ v1,
                            const float* __restrict__ s2, const float* __restrict__ b2,
                            const float* __restrict__ m2, const float* __restrict__ v2,
                            unsigned short* __restrict__ wfF0, unsigned short* __restrict__ wfF1,
                            unsigned short* __restrict__ wfF2, float* __restrict__ beta) {
    int o = blockIdx.x;
    int t = threadIdx.x;
    float inv0 = s0[o] * rsqrtf(v0[o] + BN_EPS);
    float inv1 = s1[o] * rsqrtf(v1[o] + BN_EPS);
    float inv2 = s2[o] * rsqrtf(v2[o] + BN_EPS);
    if (t == 0) {
        beta[0 * 256 + o] = b0[o] - m0[o] * inv0;
        beta[1 * 256 + o] = b1[o] - m1[o] * inv1;
        beta[2 * 256 + o] = b2[o] - m2[o] * inv2;
    }
    if (t < 128) {
        wfF0[((t >> 3) * 256 + o) * 8 + (t & 7)] = f2bf(pw0[o * 128 + t] * inv0);
        wfF1[((t >> 3) * 256 + o) * 8 + (t & 7)] = f2bf(pw1[o * 128 + t] * inv1);
    }
    wfF2[((t >> 3) * 256 + o) * 8 + (t & 7)] = f2bf(w2[o * 256 + t] * inv2);
}

// ---------------- GEMM helper: chunked A-preload (4 kk in flight) ---------------------
// B-tile: [64 px][256 K] bf16, px-major 512 B/px, 16-B col c stored at c ^ ((px&15)<<4).
template<int NK>
__device__ __forceinline__ void gemm_expert(const char* lds, const unsigned short* __restrict__ W,
                                            int qb, int wave, int l15, int l4,
                                            const int* pxv, const int* swv, f32x4 acc[2][4]) {
    const int row0 = wave * 32 + l15;
#pragma unroll
    for (int ck = 0; ck < NK; ck += 4) {
        // A-chunk: 8 fragments (32 VGPRs), one independent L2 round-trip
        bf16x8 af[4][2];
#pragma unroll
        for (int kk = 0; kk < 4; ++kk)
#pragma unroll
            for (int ot = 0; ot < 2; ++ot)
                af[kk][ot] = *(const bf16x8*)(W + (((ck + kk) * 4 + l4) * 256 + row0 + ot * 16) * 8);
#pragma unroll
        for (int kk = 0; kk < 4; ++kk) {
            bf16x8 bb[4];
#pragma unroll
            for (int tp = 0; tp < 4; ++tp)
                bb[tp] = *(const bf16x8*)(lds + pxv[tp] * 512 + ((qb + (ck + kk) * 64 + l4 * 16) ^ swv[tp]));
#pragma unroll
            for (int ot = 0; ot < 2; ++ot)
#pragma unroll
                for (int tp = 0; tp < 4; ++tp)
                    acc[ot][tp] = __builtin_amdgcn_mfma_f32_16x16x32_bf16(af[kk][ot], bb[tp], acc[ot][tp], 0, 0, 0);
        }
    }
}

__device__ __forceinline__ void epilogue(const f32x4 acc[2][4], float ce, const float* __restrict__ bp,
                                         int wave, int l4, f32x4 res[2][4]) {
#pragma unroll
    for (int ot = 0; ot < 2; ++ot)
#pragma unroll
        for (int j = 0; j < 4; ++j) {
            const int o = wave * 32 + ot * 16 + l4 * 4 + j;
            const float bet = bp[o];
#pragma unroll
            for (int tp = 0; tp < 4; ++tp) {
                float v = acc[ot][tp][j] + bet;
                float sig = __builtin_amdgcn_rcpf(1.f + __expf(-v));
                res[ot][tp][j] += ce * (v * sig);
            }
        }
}

// ---------------- main fused kernel: 1 WG per (b,h) row, 8 waves, 2 K-passes ----------
// launch_bounds(512,3): registers for deep load batching; 34.8 KB LDS keeps 2 blocks/CU.
__global__ __launch_bounds__(512, 3)
void fused_kernel(const float* __restrict__ x,
                  const float* __restrict__ wts, const int* __restrict__ idx,
                  const float* __restrict__ dw0, const float* __restrict__ dw1,
                  const unsigned short* __restrict__ wfF0,
                  const unsigned short* __restrict__ wfF1,
                  const unsigned short* __restrict__ wfF2,
                  const float* __restrict__ beta,
                  float* __restrict__ out) {
    __shared__ __align__(16) char lds[34816];

    const int tid  = threadIdx.x;
    const int wave = tid >> 6;
    const int lane = tid & 63;

    // Stripe swizzle (r15): XCD x handles h-stripe [8x,8x+8) of every batch.
    const int bid = blockIdx.x;
    const int xcd = bid & 7;
    const int j   = bid >> 3;                        // 0..255
    const int b   = j >> 3;                          // 0..31
    const int h   = xcd * 8 + (j & 7);               // 0..63

    float c0 = 0.f, c1 = 0.f, c2 = 0.f;
#pragma unroll
    for (int t = 0; t < 2; ++t) {
        int e = idx[b * 2 + t];
        float w = wts[b * 2 + t];
        if (e == 0) c0 += w;
        else if (e == 1) c1 += w;
        else if (e == 2) c2 += w;
    }
    const bool do0 = (c0 != 0.f), do1 = (c1 != 0.f), do2 = (c2 != 0.f);

    const long rowBase = (long)b * 1048576L;

    const int g   = lane >> 2;
    const int kq  = lane & 3;
    const int px0 = g * 4;
    const int l15 = lane & 15;
    const int l4  = lane >> 4;
    const float* xb = x + rowBase + h * 64 + px0;
    const bool hm = (h > 0), hp = (h < 63);

    int pxv[4], swv[4];
#pragma unroll
    for (int tp = 0; tp < 4; ++tp) {
        pxv[tp] = tp * 16 + l15;
        swv[tp] = (pxv[tp] & 15) << 4;
    }

    // ================= pass 1: depthwise experts (K 0..255 = dw0 | dw1) ==============
    // Full-burst staging: all 24 float4 loads issued in one independent batch.
    if (do0 || do1) {
        if ((wave < 4) ? do0 : do1) {
            float4 RM[8], RC[8], RP[8];
            const float4 z4 = make_float4(0.f, 0.f, 0.f, 0.f);
#pragma unroll
            for (int c = 0; c < 8; ++c) {
                const int k = wave * 32 + ((c >> 2) << 4) + kq * 4 + (c & 3);
                const float* xc = xb + (long)k * 4096;
                RM[c] = hm ? *(const float4*)(xc - 64) : z4;
                RC[c] = *(const float4*)(xc);
                RP[c] = hp ? *(const float4*)(xc + 64) : z4;
            }
#pragma unroll
            for (int i = 0; i < 2; ++i) {
                const int k0 = wave * 32 + i * 16 + kq * 4;
                unsigned dw_p[2][4];
#pragma unroll
                for (int pr = 0; pr < 2; ++pr) {
                    float y[2][4];
#pragma unroll
                    for (int k2 = 0; k2 < 2; ++k2) {
                        const int c  = i * 4 + pr * 2 + k2;
                        const int k  = k0 + pr * 2 + k2;
                        const float* dwp = (k < 128) ? (dw0 + k * 9) : (dw1 + (k - 128) * 9);
                        float4 rm = RM[c], rc = RC[c], rp = RP[c];
                        float lm = __shfl_up(rm.w, 4), lc = __shfl_up(rc.w, 4), lp = __shfl_up(rp.w, 4);
                        float Rm = __shfl_down(rm.x, 4), Rc = __shfl_down(rc.x, 4), Rp = __shfl_down(rp.x, 4);
                        if (g == 0)  { lm = 0.f; lc = 0.f; lp = 0.f; }
                        if (g == 15) { Rm = 0.f; Rc = 0.f; Rp = 0.f; }
                        const float w0 = dwp[0], w1 = dwp[1], w2 = dwp[2];
                        const float w3 = dwp[3], w4 = dwp[4], w5 = dwp[5];
                        const float w6 = dwp[6], w7 = dwp[7], w8 = dwp[8];
                        y[k2][0] = w0*lm   + w1*rm.x + w2*rm.y + w3*lc   + w4*rc.x + w5*rc.y + w6*lp   + w7*rp.x + w8*rp.y;
                        y[k2][1] = w0*rm.x + w1*rm.y + w2*rm.z + w3*rc.x + w4*rc.y + w5*rc.z + w6*rp.x + w7*rp.y + w8*rp.z;
                        y[k2][2] = w0*rm.y + w1*rm.z + w2*rm.w + w3*rc.y + w4*rc.z + w5*rc.w + w6*rp.y + w7*rp.z + w8*rp.w;
                        y[k2][3] = w0*rm.z + w1*rm.w + w2*Rm   + w3*rc.z + w4*rc.w + w5*Rc   + w6*rp.z + w7*rp.w + w8*Rp;
                    }
#pragma unroll
                    for (int j2 = 0; j2 < 4; ++j2)
                        dw_p[pr][j2] = pk_bf16(y[0][j2], y[1][j2]);
                }
                const int colb = (k0 >> 3) * 16;
                const int sub  = (k0 & 4) * 2;
#pragma unroll
                for (int j2 = 0; j2 < 4; ++j2) {
                    const int px = px0 + j2;
                    *(uint2*)(lds + px * 512 + ((colb ^ ((px & 15) << 4))) + sub) =
                        make_uint2(dw_p[0][j2], dw_p[1][j2]);
                }
            }
        }
        __syncthreads();
    }

    f32x4 res[2][4];
#pragma unroll
    for (int ot = 0; ot < 2; ++ot)
#pragma unroll
        for (int tp = 0; tp < 4; ++tp)
            res[ot][tp] = (f32x4){0.f, 0.f, 0.f, 0.f};

    if (do0 || do1) {
        if (do0) {
            f32x4 acc[2][4];
#pragma unroll
            for (int ot = 0; ot < 2; ++ot)
#pragma unroll
                for (int tp = 0; tp < 4; ++tp) acc[ot][tp] = (f32x4){0.f, 0.f, 0.f, 0.f};
            gemm_expert<4>(lds, wfF0, 0, wave, l15, l4, pxv, swv, acc);
            epilogue(acc, c0, beta, wave, l4, res);
        }
        if (do1) {
            f32x4 acc[2][4];
#pragma unroll
            for (int ot = 0; ot < 2; ++ot)
#pragma unroll
                for (int tp = 0; tp < 4; ++tp) acc[ot][tp] = (f32x4){0.f, 0.f, 0.f, 0.f};
            gemm_expert<4>(lds, wfF1, 256, wave, l15, l4, pxv, swv, acc);
            epilogue(acc, c1, beta + 256, wave, l4, res);
        }
    }

    // ================= pass 2: raw expert (K 0..255 = x channels) ====================
    if (do2) {
        __syncthreads();
        {
            const int cb = wave * 32 + kq * 8;
            float4 r[8];
#pragma unroll
            for (int c = 0; c < 8; ++c)
                r[c] = *(const float4*)(xb + (long)(cb + c) * 4096);
            const int colb = (cb >> 3) * 16;
#pragma unroll
            for (int j2 = 0; j2 < 4; ++j2) {
                const int px = px0 + j2;
                float v0 = fcomp(r[0], j2), v1 = fcomp(r[1], j2), v2 = fcomp(r[2], j2), v3 = fcomp(r[3], j2);
                float v4 = fcomp(r[4], j2), v5 = fcomp(r[5], j2), v6 = fcomp(r[6], j2), v7 = fcomp(r[7], j2);
                *(uint4*)(lds + px * 512 + ((colb ^ ((px & 15) << 4)))) =
                    make_uint4(pk_bf16(v0, v1), pk_bf16(v2, v3), pk_bf16(v4, v5), pk_bf16(v6, v7));
            }
        }
        __syncthreads();
        {
            f32x4 acc[2][4];
#pragma unroll
            for (int ot = 0; ot < 2; ++ot)
#pragma unroll
                for (int tp = 0; tp < 4; ++tp) acc[ot][tp] = (f32x4){0.f, 0.f, 0.f, 0.f};
            gemm_expert<8>(lds, wfF2, 0, wave, l15, l4, pxv, swv, acc);
            epilogue(acc, c2, beta + 512, wave, l4, res);
        }
    }

    // ================= store: transpose through LDS, full-line writes ================
    float* lf = (float*)lds;
    const long outB = rowBase + h * 64;
    __syncthreads();
#pragma unroll
    for (int r = 0; r < 2; ++r) {
        if ((wave >> 2) == r) {
#pragma unroll
            for (int ot = 0; ot < 2; ++ot)
#pragma unroll
                for (int j2 = 0; j2 < 4; ++j2) {
                    const int o = wave * 32 + ot * 16 + l4 * 4 + j2;
#pragma unroll
                    for (int tp = 0; tp < 4; ++tp)
                        lf[(o & 127) * 68 + tp * 16 + l15] = res[ot][tp][j2];
                }
        }
        __syncthreads();
        {
            const int rowq = tid >> 3;
            const int col  = (tid & 7) * 8;
#pragma unroll
            for (int rr = 0; rr < 2; ++rr) {
                const int lr = rowq + rr * 64;
                float4 v0 = *(float4*)&lf[lr * 68 + col];
                float4 v1 = *(float4*)&lf[lr * 68 + col + 4];
                float* op = out + outB + (long)(r * 128 + lr) * 4096 + col;
                *(float4*)op = v0;
                *(float4*)(op + 4) = v1;
            }
        }
        if (r == 0) __syncthreads();                 // final barrier after last read is dead
    }
}

extern "C" void kernel_launch(void* const* d_in, const int* in_sizes, int n_in,
                              void* d_out, int out_size, void* d_ws, size_t ws_size,
                              hipStream_t stream) {
    const float* x    = (const float*)d_in[0];
    const float* wts  = (const float*)d_in[1];
    const int*   idx  = (const int*)d_in[2];
    const float* dw0  = (const float*)d_in[3];
    const float* pw0  = (const float*)d_in[4];
    const float* s0   = (const float*)d_in[5];
    const float* b0   = (const float*)d_in[6];
    const float* m0   = (const float*)d_in[7];
    const float* v0   = (const float*)d_in[8];
    const float* dw1  = (const float*)d_in[9];
    const float* pw1  = (const float*)d_in[10];
    const float* s1   = (const float*)d_in[11];
    const float* b1   = (const float*)d_in[12];
    const float* m1   = (const float*)d_in[13];
    const float* v1   = (const float*)d_in[14];
    const float* w2   = (const float*)d_in[15];
    const float* s2   = (const float*)d_in[16];
    const float* b2   = (const float*)d_in[17];
    const float* m2   = (const float*)d_in[18];
    const float* v2   = (const float*)d_in[19];

    char* ws = (char*)d_ws;
    unsigned short* wfF0 = (unsigned short*)ws;                 // 64 KB
    unsigned short* wfF1 = (unsigned short*)(ws + 65536);       // 64 KB
    unsigned short* wfF2 = (unsigned short*)(ws + 131072);      // 128 KB
    float*          beta = (float*)(ws + 262144);               // 3 KB

    prep_kernel<<<256, 256, 0, stream>>>(pw0, pw1, w2,
                                         s0, b0, m0, v0,
                                         s1, b1, m1, v1,
                                         s2, b2, m2, v2,
                                         wfF0, wfF1, wfF2, beta);

    fused_kernel<<<2048, 512, 0, stream>>>(x, wts, idx, dw0, dw1,
                                           wfF0, wfF1, wfF2, beta, (float*)d_out);
}

// Round 20
// 82.452 us; speedup vs baseline: 1.2955x; 1.0094x over previous
//
#include <hip/hip_runtime.h>

typedef __bf16 bf16x8 __attribute__((ext_vector_type(8)));
typedef float f32x4 __attribute__((ext_vector_type(4)));

#define BN_EPS 1e-5f

__device__ __forceinline__ unsigned short f2bf(float f) {
    union { float f; unsigned u; } x; x.f = f;
    unsigned r = x.u + 0x7fffu + ((x.u >> 16) & 1u);
    return (unsigned short)(r >> 16);
}

__device__ __forceinline__ unsigned pk_bf16(float lo, float hi) {
    unsigned r;
    asm("v_cvt_pk_bf16_f32 %0, %1, %2" : "=v"(r) : "v"(lo), "v"(hi));
    return r;
}

__device__ __forceinline__ float fcomp(float4 v, int j) {
    return (j == 0) ? v.x : (j == 1) ? v.y : (j == 2) ? v.z : v.w;
}

// ---------------- prepass: fold BN scale into weights, FRAGMENT-CONTIGUOUS layout ----
__global__ void prep_kernel(const float* __restrict__ pw0, const float* __restrict__ pw1,
                            const float* __restrict__ w2,
                            const float* __restrict__ s0, const float* __restrict__ b0,
                            const float* __restrict__ m0, const float* __restrict__ v0,
                            const float* __restrict__ s1, const float* __restrict__ b1,
                            const float* __restrict__ m1, const float* __restrict__ v1,
                            const float* __restrict__ s2, const float* __restrict__ b2,
                            const float* __restrict__ m2, const float* __restrict__ v2,
                            unsigned short* __restrict__ wfF0, unsigned short* __restrict__ wfF1,
                            unsigned short* __restrict__ wfF2, float* __restrict__ beta) {
    int o = blockIdx.x;
    int t = threadIdx.x;
    float inv0 = s0[o] * rsqrtf(v0[o] + BN_EPS);
    float inv1 = s1[o] * rsqrtf(v1[o] + BN_EPS);
    float inv2 = s2[o] * rsqrtf(v2[o] + BN_EPS);
    if (t == 0) {
        beta[0 * 256 + o] = b0[o] - m0[o] * inv0;
        beta[1 * 256 + o] = b1[o] - m1[o] * inv1;
        beta[2 * 256 + o] = b2[o] - m2[o] * inv2;
    }
    if (t < 128) {
        wfF0[((t >> 3) * 256 + o) * 8 + (t & 7)] = f2bf(pw0[o * 128 + t] * inv0);
        wfF1[((t >> 3) * 256 + o) * 8 + (t & 7)] = f2bf(pw1[o * 128 + t] * inv1);
    }
    wfF2[((t >> 3) * 256 + o) * 8 + (t & 7)] = f2bf(w2[o * 256 + t] * inv2);
}

// ---------------- GEMM helper: chunked A-preload (4 kk in flight) ---------------------
// B-tile: [64 px][256 K] bf16, px-major 512 B/px, 16-B col c stored at c ^ ((px&15)<<4).
template<int NK>
__device__ __forceinline__ void gemm_expert(const char* lds, const unsigned short* __restrict__ W,
                                            int qb, int wave, int l15, int l4,
                                            const int* pxv, const int* swv, f32x4 acc[2][4]) {
    const int row0 = wave * 32 + l15;
#pragma unroll
    for (int ck = 0; ck < NK; ck += 4) {
        // A-chunk: 8 fragments (32 VGPRs), one independent L2 round-trip
        bf16x8 af[4][2];
#pragma unroll
        for (int kk = 0; kk < 4; ++kk)
#pragma unroll
            for (int ot = 0; ot < 2; ++ot)
                af[kk][ot] = *(const bf16x8*)(W + (((ck + kk) * 4 + l4) * 256 + row0 + ot * 16) * 8);
#pragma unroll
        for (int kk = 0; kk < 4; ++kk) {
            bf16x8 bb[4];
#pragma unroll
            for (int tp = 0; tp < 4; ++tp)
                bb[tp] = *(const bf16x8*)(lds + pxv[tp] * 512 + ((qb + (ck + kk) * 64 + l4 * 16) ^ swv[tp]));
#pragma unroll
            for (int ot = 0; ot < 2; ++ot)
#pragma unroll
                for (int tp = 0; tp < 4; ++tp)
                    acc[ot][tp] = __builtin_amdgcn_mfma_f32_16x16x32_bf16(af[kk][ot], bb[tp], acc[ot][tp], 0, 0, 0);
        }
    }
}

__device__ __forceinline__ void epilogue(const f32x4 acc[2][4], float ce, const float* __restrict__ bp,
                                         int wave, int l4, f32x4 res[2][4]) {
#pragma unroll
    for (int ot = 0; ot < 2; ++ot)
#pragma unroll
        for (int j = 0; j < 4; ++j) {
            const int o = wave * 32 + ot * 16 + l4 * 4 + j;
            const float bet = bp[o];
#pragma unroll
            for (int tp = 0; tp < 4; ++tp) {
                float v = acc[ot][tp][j] + bet;
                float sig = __builtin_amdgcn_rcpf(1.f + __expf(-v));
                res[ot][tp][j] += ce * (v * sig);
            }
        }
}

// ---------------- main fused kernel: 1 WG per (b,h) row, 8 waves, 2 K-passes ----------
// launch_bounds(512,4): A/B vs r19 — chunked-A + 2-block/CU co-residency (128-reg budget).
__global__ __launch_bounds__(512, 4)
void fused_kernel(const float* __restrict__ x,
                  const float* __restrict__ wts, const int* __restrict__ idx,
                  const float* __restrict__ dw0, const float* __restrict__ dw1,
                  const unsigned short* __restrict__ wfF0,
                  const unsigned short* __restrict__ wfF1,
                  const unsigned short* __restrict__ wfF2,
                  const float* __restrict__ beta,
                  float* __restrict__ out) {
    __shared__ __align__(16) char lds[34816];

    const int tid  = threadIdx.x;
    const int wave = tid >> 6;
    const int lane = tid & 63;

    // Stripe swizzle (r15): XCD x handles h-stripe [8x,8x+8) of every batch.
    const int bid = blockIdx.x;
    const int xcd = bid & 7;
    const int j   = bid >> 3;                        // 0..255
    const int b   = j >> 3;                          // 0..31
    const int h   = xcd * 8 + (j & 7);               // 0..63

    float c0 = 0.f, c1 = 0.f, c2 = 0.f;
#pragma unroll
    for (int t = 0; t < 2; ++t) {
        int e = idx[b * 2 + t];
        float w = wts[b * 2 + t];
        if (e == 0) c0 += w;
        else if (e == 1) c1 += w;
        else if (e == 2) c2 += w;
    }
    const bool do0 = (c0 != 0.f), do1 = (c1 != 0.f), do2 = (c2 != 0.f);

    const long rowBase = (long)b * 1048576L;

    const int g   = lane >> 2;
    const int kq  = lane & 3;
    const int px0 = g * 4;
    const int l15 = lane & 15;
    const int l4  = lane >> 4;
    const float* xb = x + rowBase + h * 64 + px0;
    const bool hm = (h > 0), hp = (h < 63);

    int pxv[4], swv[4];
#pragma unroll
    for (int tp = 0; tp < 4; ++tp) {
        pxv[tp] = tp * 16 + l15;
        swv[tp] = (pxv[tp] & 15) << 4;
    }

    // ================= pass 1: depthwise experts (K 0..255 = dw0 | dw1) ==============
    // Full-burst staging: all 24 float4 loads issued in one independent batch.
    if (do0 || do1) {
        if ((wave < 4) ? do0 : do1) {
            float4 RM[8], RC[8], RP[8];
            const float4 z4 = make_float4(0.f, 0.f, 0.f, 0.f);
#pragma unroll
            for (int c = 0; c < 8; ++c) {
                const int k = wave * 32 + ((c >> 2) << 4) + kq * 4 + (c & 3);
                const float* xc = xb + (long)k * 4096;
                RM[c] = hm ? *(const float4*)(xc - 64) : z4;
                RC[c] = *(const float4*)(xc);
                RP[c] = hp ? *(const float4*)(xc + 64) : z4;
            }
#pragma unroll
            for (int i = 0; i < 2; ++i) {
                const int k0 = wave * 32 + i * 16 + kq * 4;
                unsigned dw_p[2][4];
#pragma unroll
                for (int pr = 0; pr < 2; ++pr) {
                    float y[2][4];
#pragma unroll
                    for (int k2 = 0; k2 < 2; ++k2) {
                        const int c  = i * 4 + pr * 2 + k2;
                        const int k  = k0 + pr * 2 + k2;
                        const float* dwp = (k < 128) ? (dw0 + k * 9) : (dw1 + (k - 128) * 9);
                        float4 rm = RM[c], rc = RC[c], rp = RP[c];
                        float lm = __shfl_up(rm.w, 4), lc = __shfl_up(rc.w, 4), lp = __shfl_up(rp.w, 4);
                        float Rm = __shfl_down(rm.x, 4), Rc = __shfl_down(rc.x, 4), Rp = __shfl_down(rp.x, 4);
                        if (g == 0)  { lm = 0.f; lc = 0.f; lp = 0.f; }
                        if (g == 15) { Rm = 0.f; Rc = 0.f; Rp = 0.f; }
                        const float w0 = dwp[0], w1 = dwp[1], w2 = dwp[2];
                        const float w3 = dwp[3], w4 = dwp[4], w5 = dwp[5];
                        const float w6 = dwp[6], w7 = dwp[7], w8 = dwp[8];
                        y[k2][0] = w0*lm   + w1*rm.x + w2*rm.y + w3*lc   + w4*rc.x + w5*rc.y + w6*lp   + w7*rp.x + w8*rp.y;
                        y[k2][1] = w0*rm.x + w1*rm.y + w2*rm.z + w3*rc.x + w4*rc.y + w5*rc.z + w6*rp.x + w7*rp.y + w8*rp.z;
                        y[k2][2] = w0*rm.y + w1*rm.z + w2*rm.w + w3*rc.y + w4*rc.z + w5*rc.w + w6*rp.y + w7*rp.z + w8*rp.w;
                        y[k2][3] = w0*rm.z + w1*rm.w + w2*Rm   + w3*rc.z + w4*rc.w + w5*Rc   + w6*rp.z + w7*rp.w + w8*Rp;
                    }
#pragma unroll
                    for (int j2 = 0; j2 < 4; ++j2)
                        dw_p[pr][j2] = pk_bf16(y[0][j2], y[1][j2]);
                }
                const int colb = (k0 >> 3) * 16;
                const int sub  = (k0 & 4) * 2;
#pragma unroll
                for (int j2 = 0; j2 < 4; ++j2) {
                    const int px = px0 + j2;
                    *(uint2*)(lds + px * 512 + ((colb ^ ((px & 15) << 4))) + sub) =
                        make_uint2(dw_p[0][j2], dw_p[1][j2]);
                }
            }
        }
        __syncthreads();
    }

    f32x4 res[2][4];
#pragma unroll
    for (int ot = 0; ot < 2; ++ot)
#pragma unroll
        for (int tp = 0; tp < 4; ++tp)
            res[ot][tp] = (f32x4){0.f, 0.f, 0.f, 0.f};

    if (do0 || do1) {
        if (do0) {
            f32x4 acc[2][4];
#pragma unroll
            for (int ot = 0; ot < 2; ++ot)
#pragma unroll
                for (int tp = 0; tp < 4; ++tp) acc[ot][tp] = (f32x4){0.f, 0.f, 0.f, 0.f};
            gemm_expert<4>(lds, wfF0, 0, wave, l15, l4, pxv, swv, acc);
            epilogue(acc, c0, beta, wave, l4, res);
        }
        if (do1) {
            f32x4 acc[2][4];
#pragma unroll
            for (int ot = 0; ot < 2; ++ot)
#pragma unroll
                for (int tp = 0; tp < 4; ++tp) acc[ot][tp] = (f32x4){0.f, 0.f, 0.f, 0.f};
            gemm_expert<4>(lds, wfF1, 256, wave, l15, l4, pxv, swv, acc);
            epilogue(acc, c1, beta + 256, wave, l4, res);
        }
    }

    // ================= pass 2: raw expert (K 0..255 = x channels) ====================
    if (do2) {
        __syncthreads();
        {
            const int cb = wave * 32 + kq * 8;
            float4 r[8];
#pragma unroll
            for (int c = 0; c < 8; ++c)
                r[c] = *(const float4*)(xb + (long)(cb + c) * 4096);
            const int colb = (cb >> 3) * 16;
#pragma unroll
            for (int j2 = 0; j2 < 4; ++j2) {
                const int px = px0 + j2;
                float v0 = fcomp(r[0], j2), v1 = fcomp(r[1], j2), v2 = fcomp(r[2], j2), v3 = fcomp(r[3], j2);
                float v4 = fcomp(r[4], j2), v5 = fcomp(r[5], j2), v6 = fcomp(r[6], j2), v7 = fcomp(r[7], j2);
                *(uint4*)(lds + px * 512 + ((colb ^ ((px & 15) << 4)))) =
                    make_uint4(pk_bf16(v0, v1), pk_bf16(v2, v3), pk_bf16(v4, v5), pk_bf16(v6, v7));
            }
        }
        __syncthreads();
        {
            f32x4 acc[2][4];
#pragma unroll
            for (int ot = 0; ot < 2; ++ot)
#pragma unroll
                for (int tp = 0; tp < 4; ++tp) acc[ot][tp] = (f32x4){0.f, 0.f, 0.f, 0.f};
            gemm_expert<8>(lds, wfF2, 0, wave, l15, l4, pxv, swv, acc);
            epilogue(acc, c2, beta + 512, wave, l4, res);
        }
    }

    // ================= store: transpose through LDS, full-line writes ================
    float* lf = (float*)lds;
    const long outB = rowBase + h * 64;
    __syncthreads();
#pragma unroll
    for (int r = 0; r < 2; ++r) {
        if ((wave >> 2) == r) {
#pragma unroll
            for (int ot = 0; ot < 2; ++ot)
#pragma unroll
                for (int j2 = 0; j2 < 4; ++j2) {
                    const int o = wave * 32 + ot * 16 + l4 * 4 + j2;
#pragma unroll
                    for (int tp = 0; tp < 4; ++tp)
                        lf[(o & 127) * 68 + tp * 16 + l15] = res[ot][tp][j2];
                }
        }
        __syncthreads();
        {
            const int rowq = tid >> 3;
            const int col  = (tid & 7) * 8;
#pragma unroll
            for (int rr = 0; rr < 2; ++rr) {
                const int lr = rowq + rr * 64;
                float4 v0 = *(float4*)&lf[lr * 68 + col];
                float4 v1 = *(float4*)&lf[lr * 68 + col + 4];
                float* op = out + outB + (long)(r * 128 + lr) * 4096 + col;
                *(float4*)op = v0;
                *(float4*)(op + 4) = v1;
            }
        }
        if (r == 0) __syncthreads();                 // final barrier after last read is dead
    }
}

extern "C" void kernel_launch(void* const* d_in, const int* in_sizes, int n_in,
                              void* d_out, int out_size, void* d_ws, size_t ws_size,
                              hipStream_t stream) {
    const float* x    = (const float*)d_in[0];
    const float* wts  = (const float*)d_in[1];
    const int*   idx  = (const int*)d_in[2];
    const float* dw0  = (const float*)d_in[3];
    const float* pw0  = (const float*)d_in[4];
    const float* s0   = (const float*)d_in[5];
    const float* b0   = (const float*)d_in[6];
    const float* m0   = (const float*)d_in[7];
    const float* v0   = (const float*)d_in[8];
    const float* dw1  = (const float*)d_in[9];
    const float* pw1  = (const float*)d_in[10];
    const float* s1   = (const float*)d_in[11];
    const float* b1   = (const float*)d_in[12];
    const float* m1   = (const float*)d_in[13];
    const float* v1   = (const float*)d_in[14];
    const float* w2   = (const float*)d_in[15];
    const float* s2   = (const float*)d_in[16];
    const float* b2   = (const float*)d_in[17];
    const float* m2   = (const float*)d_in[18];
    const float* v2   = (const float*)d_in[19];

    char* ws = (char*)d_ws;
    unsigned short* wfF0 = (unsigned short*)ws;                 // 64 KB
    unsigned short* wfF1 = (unsigned short*)(ws + 65536);       // 64 KB
    unsigned short* wfF2 = (unsigned short*)(ws + 131072);      // 128 KB
    float*          beta = (float*)(ws + 262144);               // 3 KB

    prep_kernel<<<256, 256, 0, stream>>>(pw0, pw1, w2,
                                         s0, b0, m0, v0,
                                         s1, b1, m1, v1,
                                         s2, b2, m2, v2,
                                         wfF0, wfF1, wfF2, beta);

    fused_kernel<<<2048, 512, 0, stream>>>(x, wts, idx, dw0, dw1,
                                           wfF0, wfF1, wfF2, beta, (float*)d_out);
}